// Round 8
// baseline (243.982 us; speedup 1.0000x reference)
//
#include <hip/hip_runtime.h>
#include <math.h>

// dims
#define B_   64
#define N1_  1152
#define P_   8
#define N2_  128
#define D_   16

#define NSPLIT 32                      // i-splits for k1/k3c partials
#define CHUNK  (N1_ / NSPLIT)          // 36 i per chunk
#define NIB    (CHUNK / 4)             // 9 i-blocks of 4

typedef __attribute__((ext_vector_type(8)))  short bf16x8;
typedef __attribute__((ext_vector_type(4)))  float f32x4;
typedef __attribute__((ext_vector_type(16))) float f32x16;

// split 8 fp32 into hi/lo bf16 fragments (hi = truncate, lo = bf16(w - hi))
__device__ inline void split_frag(float4 a0, float4 a1, bf16x8& hi, bf16x8& lo)
{
    float w[8] = {a0.x, a0.y, a0.z, a0.w, a1.x, a1.y, a1.z, a1.w};
#pragma unroll
    for (int j = 0; j < 8; ++j) {
        unsigned ub = __float_as_uint(w[j]);
        hi[j] = (short)(ub >> 16);
        float hif = __uint_as_float(ub & 0xffff0000u);
        float r = w[j] - hif;
        lo[j] = (short)(__float_as_uint(r) >> 16);
    }
}

__device__ inline void split_arr(const float* w, bf16x8& hi, bf16x8& lo)
{
#pragma unroll
    for (int j = 0; j < 8; ++j) {
        unsigned ub = __float_as_uint(w[j]);
        hi[j] = (short)(ub >> 16);
        float hif = __uint_as_float(ub & 0xffff0000u);
        float r = w[j] - hif;
        lo[j] = (short)(__float_as_uint(r) >> 16);
    }
}

// ---------------------------------------------------------------------------
// K1 (MFMA, validated r4): s0p[isp][b][n][d] = sum_{i in chunk, p} W[i,n,d,p]*x[b,i,p]
// ---------------------------------------------------------------------------
__global__ __launch_bounds__(256) void k1_s0_mfma(const float* __restrict__ x,
                                                  const float* __restrict__ W,
                                                  float* __restrict__ s0p)
{
    const int tid   = threadIdx.x;
    const int lane  = tid & 63;
    const int wv    = tid >> 6;
    const int col   = lane & 15;
    const int quad  = lane >> 4;
    const int b     = wv * 16 + col;
    const int nbase = blockIdx.x * 4;
    const int isp   = blockIdx.y;
    const int ibase = isp * CHUNK;

    f32x4 acc[4];
#pragma unroll
    for (int nn = 0; nn < 4; ++nn) acc[nn] = (f32x4){0.f, 0.f, 0.f, 0.f};

    const float* xlane = x + ((size_t)b * N1_ + ibase + quad) * P_;

    for (int ib = 0; ib < NIB; ++ib) {
        const int i0 = ibase + ib * 4;
        float4 xa = *(const float4*)(xlane);
        float4 xb = *(const float4*)(xlane + 4);
        xlane += 4 * P_;
        bf16x8 bhi, blo;
        split_frag(xa, xb, bhi, blo);
#pragma unroll
        for (int nn = 0; nn < 4; ++nn) {
            const float* wp = W + (((size_t)(i0 + quad) * N2_ + nbase + nn) * D_ + col) * P_;
            float4 wa = *(const float4*)wp;
            float4 wb = *(const float4*)(wp + 4);
            bf16x8 ahi, alo;
            split_frag(wa, wb, ahi, alo);
            acc[nn] = __builtin_amdgcn_mfma_f32_16x16x32_bf16(ahi, bhi, acc[nn], 0, 0, 0);
            acc[nn] = __builtin_amdgcn_mfma_f32_16x16x32_bf16(ahi, blo, acc[nn], 0, 0, 0);
            acc[nn] = __builtin_amdgcn_mfma_f32_16x16x32_bf16(alo, bhi, acc[nn], 0, 0, 0);
        }
    }
#pragma unroll
    for (int nn = 0; nn < 4; ++nn) {
        float4 v = make_float4(acc[nn][0], acc[nn][1], acc[nn][2], acc[nn][3]);
        *(float4*)(s0p + (size_t)isp * (B_ * N2_ * D_) + (size_t)b * (N2_ * D_)
                   + (nbase + nn) * D_ + quad * 4) = v;
    }
}

// ---------------------------------------------------------------------------
// K2/K4: reduce nsplit partials, scale, squash over d (16), write v.
// ---------------------------------------------------------------------------
__global__ __launch_bounds__(256) void k2_squash(const float* __restrict__ spart,
                                                 float* __restrict__ vout,
                                                 float scale, int nsplit)
{
    int idx = blockIdx.x * 256 + threadIdx.x;   // 0 .. 131071
    float s = 0.f;
    for (int sp = 0; sp < nsplit; ++sp)
        s += spart[(size_t)sp * (B_ * N2_ * D_) + idx];
    s *= scale;
    float sq = s * s;
    sq += __shfl_xor(sq, 1);
    sq += __shfl_xor(sq, 2);
    sq += __shfl_xor(sq, 4);
    sq += __shfl_xor(sq, 8);
    float norm = sqrtf(sq + 1.1920929e-7f);
    vout[idx] = (sq / (1.f + sq)) * (s / norm);
}

// ---------------------------------------------------------------------------
// K3A (MFMA 32x32x16): raw_t[i][n][b] = sum_d v0[b,n,d]*(sum_p W[i,n,d,p]*x[b,i,p])
// Y[(isub,p), b] = sum_d W[i0+isub,n,d,p] * v0[b,n,d]  -- M=32=(4i x 8p), K=d=16
// (exact, no zero K-half), N=32 b per MFMA (2 tiles cover 64 b).
// A-lane (m=lane&31 -> isub=m>>3, p=m&7; kh=lane>>5): W[i0+isub,n,d=kh*8+j,p]
//   8 scalar loads, ALL 64 lanes active (8 x 32B segments per instr).
// B-lane (col=m=b, kh): v0[b,n,d=kh*8+j] contiguous f4x2, split once per block.
// C/D (verified m74/m101): col=lane&31, row=(reg&3)+8*(reg>>2)+4*kh
//   -> isub=reg>>2, p=(reg&3)+4*kh: epilogue dot4 with x[b,i0+isub,kh*4..+3],
//   one shfl_xor(32) combines p-halves; kh==0 stores 128B-contiguous rows.
// grid (128 n, 18 chunks of 64 i); 4 fully-unrolled iters/wave. No LDS/barriers.
// ---------------------------------------------------------------------------
__global__ __launch_bounds__(256, 4) void k3a_mfma32(const float* __restrict__ x,
                                                     const float* __restrict__ W,
                                                     const float* __restrict__ v0,
                                                     float* __restrict__ raw_t)
{
    const int tid  = threadIdx.x;
    const int lane = tid & 63;
    const int wv   = tid >> 6;
    const int m    = lane & 31;
    const int kh   = lane >> 5;         // k-half (d-half)
    const int isub = m >> 3;
    const int p    = m & 7;
    const int n    = blockIdx.x;
    const int ichunk = blockIdx.y * 64;

    // B fragments (i-invariant): v0 for 2 b-tiles of 32, split once
    bf16x8 vhi[2], vlo[2];
#pragma unroll
    for (int bt = 0; bt < 2; ++bt) {
        const float* vp = v0 + (size_t)(bt * 32 + m) * (N2_ * D_) + n * D_ + kh * 8;
        float4 qa = *(const float4*)vp;
        float4 qb = *(const float4*)(vp + 4);
        split_frag(qa, qb, vhi[bt], vlo[bt]);
    }

#pragma unroll
    for (int k4 = 0; k4 < 4; ++k4) {
        const int i0 = ichunk + (wv + 4 * k4) * 4;      // 4 i's this iter
        // A gather: 8 dwords, stride 32 B, full-lane
        const float* wp = W + ((size_t)(i0 + isub) * N2_ + n) * (D_ * P_) + kh * 64 + p;
        float a[8];
#pragma unroll
        for (int j = 0; j < 8; ++j) a[j] = wp[8 * j];
        bf16x8 ahi, alo;
        split_arr(a, ahi, alo);

        f32x16 acc0 = {0.f}, acc1 = {0.f};
#pragma unroll
        for (int r = 0; r < 16; ++r) { acc0[r] = 0.f; acc1[r] = 0.f; }
        acc0 = __builtin_amdgcn_mfma_f32_32x32x16_bf16(ahi, vhi[0], acc0, 0, 0, 0);
        acc0 = __builtin_amdgcn_mfma_f32_32x32x16_bf16(ahi, vlo[0], acc0, 0, 0, 0);
        acc0 = __builtin_amdgcn_mfma_f32_32x32x16_bf16(alo, vhi[0], acc0, 0, 0, 0);
        acc1 = __builtin_amdgcn_mfma_f32_32x32x16_bf16(ahi, vhi[1], acc1, 0, 0, 0);
        acc1 = __builtin_amdgcn_mfma_f32_32x32x16_bf16(ahi, vlo[1], acc1, 0, 0, 0);
        acc1 = __builtin_amdgcn_mfma_f32_32x32x16_bf16(alo, vhi[1], acc1, 0, 0, 0);

        // epilogue: fold x over p, combine d? no - combine p-halves (kh) by shfl
#pragma unroll
        for (int bt = 0; bt < 2; ++bt) {
            const int b = bt * 32 + m;
#pragma unroll
            for (int is = 0; is < 4; ++is) {
                float4 x4 = *(const float4*)(x + ((size_t)b * N1_ + i0 + is) * P_ + kh * 4);
                float r;
                if (bt == 0)
                    r = acc0[4 * is] * x4.x + acc0[4 * is + 1] * x4.y
                      + acc0[4 * is + 2] * x4.z + acc0[4 * is + 3] * x4.w;
                else
                    r = acc1[4 * is] * x4.x + acc1[4 * is + 1] * x4.y
                      + acc1[4 * is + 2] * x4.z + acc1[4 * is + 3] * x4.w;
                r += __shfl_xor(r, 32);
                if (kh == 0)
                    raw_t[(size_t)(i0 + is) * (N2_ * 64) + n * 64 + b] = r;
            }
        }
    }
}

// ---------------------------------------------------------------------------
// K3B_T: in-place softmax over n on raw_t[i][n][b] -> c_t[i][n][b].
// ---------------------------------------------------------------------------
__global__ __launch_bounds__(256) void k3b_t(float* __restrict__ rawc)
{
    const int i  = blockIdx.x;
    const int t  = threadIdx.x;
    const int b  = t & 63;
    const int ng = t >> 6;
    float* base = rawc + (size_t)i * (N2_ * 64) + b;

    float v[32];
    float m = -1e30f;
#pragma unroll
    for (int k = 0; k < 32; ++k) {
        v[k] = base[(ng * 32 + k) * 64];
        m = fmaxf(m, v[k]);
    }
    __shared__ float red[4][64];
    red[ng][b] = m;
    __syncthreads();
    m = fmaxf(fmaxf(red[0][b], red[1][b]), fmaxf(red[2][b], red[3][b]));
    float s = 0.f;
#pragma unroll
    for (int k = 0; k < 32; ++k) { v[k] = __expf(v[k] - m); s += v[k]; }
    __syncthreads();
    red[ng][b] = s;
    __syncthreads();
    s = red[0][b] + red[1][b] + red[2][b] + red[3][b];
    float inv = 1.f / s;
#pragma unroll
    for (int k = 0; k < 32; ++k)
        base[(ng * 32 + k) * 64] = v[k] * inv;
}

// ---------------------------------------------------------------------------
// K3C (MFMA, r6): s1p[isp][b][n][d] = sum_{i,p} W[i,n,d,p]*c[b,i,n]*x[b,i,p]
// ---------------------------------------------------------------------------
__global__ __launch_bounds__(256) void k3c_s1_mfma(const float* __restrict__ x,
                                                   const float* __restrict__ W,
                                                   const float* __restrict__ c_t,
                                                   float* __restrict__ s1p)
{
    const int tid   = threadIdx.x;
    const int lane  = tid & 63;
    const int wv    = tid >> 6;
    const int col   = lane & 15;
    const int quad  = lane >> 4;
    const int n     = blockIdx.x * 4 + wv;
    const int isp   = blockIdx.y;
    const int ibase = isp * CHUNK;

    f32x4 acc[4];
#pragma unroll
    for (int bt = 0; bt < 4; ++bt) acc[bt] = (f32x4){0.f, 0.f, 0.f, 0.f};

    for (int ib = 0; ib < NIB; ++ib) {
        const int iq = ibase + ib * 4 + quad;
        const float* wp = W + ((size_t)iq * N2_ + n) * (D_ * P_) + col * P_;
        float4 wa = *(const float4*)wp;
        float4 wb = *(const float4*)(wp + 4);
        bf16x8 ahi, alo;
        split_frag(wa, wb, ahi, alo);
#pragma unroll
        for (int bt = 0; bt < 4; ++bt) {
            const int b = bt * 16 + col;
            const float* xp = x + ((size_t)b * N1_ + iq) * P_;
            float4 xa = *(const float4*)xp;
            float4 xb = *(const float4*)(xp + 4);
            float c = c_t[((size_t)iq * N2_ + n) * 64 + b];
            float4 ya = make_float4(xa.x * c, xa.y * c, xa.z * c, xa.w * c);
            float4 yb = make_float4(xb.x * c, xb.y * c, xb.z * c, xb.w * c);
            bf16x8 bhi, blo;
            split_frag(ya, yb, bhi, blo);
            acc[bt] = __builtin_amdgcn_mfma_f32_16x16x32_bf16(ahi, bhi, acc[bt], 0, 0, 0);
            acc[bt] = __builtin_amdgcn_mfma_f32_16x16x32_bf16(ahi, blo, acc[bt], 0, 0, 0);
            acc[bt] = __builtin_amdgcn_mfma_f32_16x16x32_bf16(alo, bhi, acc[bt], 0, 0, 0);
        }
    }
#pragma unroll
    for (int bt = 0; bt < 4; ++bt) {
        const int b = bt * 16 + col;
        float4 v = make_float4(acc[bt][0], acc[bt][1], acc[bt][2], acc[bt][3]);
        *(float4*)(s1p + (size_t)isp * (B_ * N2_ * D_) + (size_t)b * (N2_ * D_)
                   + n * D_ + quad * 4) = v;
    }
}

// ---------------------------------------------------------------------------
extern "C" void kernel_launch(void* const* d_in, const int* in_sizes, int n_in,
                              void* d_out, int out_size, void* d_ws, size_t ws_size,
                              hipStream_t stream)
{
    const float* x = (const float*)d_in[0];   // [64,1152,8]
    const float* W = (const float*)d_in[1];   // [1152,128,16,8]
    float* out = (float*)d_out;               // [64,128,16]

    float* s_part = (float*)d_ws;                               // 32*131072 floats (16.8 MB)
    float* v0     = s_part + (size_t)NSPLIT * B_ * N2_ * D_;    // 131072 floats
    float* c_t    = v0 + B_ * N2_ * D_;                         // 9437184 floats: raw_t then (in-place) c_t, [i][n][b]

    k1_s0_mfma  <<<dim3(32, NSPLIT), 256, 0, stream>>>(x, W, s_part);
    k2_squash   <<<512,              256, 0, stream>>>(s_part, v0, 1.f / 128.f, NSPLIT);
    k3a_mfma32  <<<dim3(128, 18),    256, 0, stream>>>(x, W, v0, c_t);
    k3b_t       <<<N1_,              256, 0, stream>>>(c_t);
    k3c_s1_mfma <<<dim3(32, NSPLIT), 256, 0, stream>>>(x, W, c_t, s_part);
    k2_squash   <<<512,              256, 0, stream>>>(s_part, out, 1.f, NSPLIT);
}

// Round 9
// 205.180 us; speedup vs baseline: 1.1891x; 1.1891x over previous
//
#include <hip/hip_runtime.h>
#include <math.h>

// dims
#define B_   64
#define N1_  1152
#define P_   8
#define N2_  128
#define D_   16

#define NSPLIT 32                      // i-splits for k1/k3c partials
#define CHUNK  (N1_ / NSPLIT)          // 36 i per chunk
#define NIB    (CHUNK / 4)             // 9 i-blocks of 4

typedef __attribute__((ext_vector_type(8)))  short bf16x8;
typedef __attribute__((ext_vector_type(4)))  float f32x4;
typedef __attribute__((ext_vector_type(16))) float f32x16;

// split 8 fp32 into hi/lo bf16 fragments (hi = truncate, lo = bf16(w - hi))
__device__ inline void split_frag(float4 a0, float4 a1, bf16x8& hi, bf16x8& lo)
{
    float w[8] = {a0.x, a0.y, a0.z, a0.w, a1.x, a1.y, a1.z, a1.w};
#pragma unroll
    for (int j = 0; j < 8; ++j) {
        unsigned ub = __float_as_uint(w[j]);
        hi[j] = (short)(ub >> 16);
        float hif = __uint_as_float(ub & 0xffff0000u);
        float r = w[j] - hif;
        lo[j] = (short)(__float_as_uint(r) >> 16);
    }
}

__device__ inline void split_arr(const float* w, bf16x8& hi, bf16x8& lo)
{
#pragma unroll
    for (int j = 0; j < 8; ++j) {
        unsigned ub = __float_as_uint(w[j]);
        hi[j] = (short)(ub >> 16);
        float hif = __uint_as_float(ub & 0xffff0000u);
        float r = w[j] - hif;
        lo[j] = (short)(__float_as_uint(r) >> 16);
    }
}

// ---------------------------------------------------------------------------
// K0: transpose x[b][i][p] -> xt[i][b][p].  Write side fully coalesced (2 KB
// rows); read side 32 lines/instr — tiny one-shot cost, removes the 64-line
// scatters from the three hot kernels.
// ---------------------------------------------------------------------------
__global__ __launch_bounds__(128) void k0_xt(const float* __restrict__ x,
                                             float* __restrict__ xt)
{
    const int i  = blockIdx.x;
    const int t  = threadIdx.x;
    const int b  = t >> 1, ph = t & 1;
    float4 v = *(const float4*)(x + ((size_t)b * N1_ + i) * P_ + ph * 4);
    *(float4*)(xt + ((size_t)i * 64 + b) * P_ + ph * 4) = v;
}

// ---------------------------------------------------------------------------
// K1 (MFMA): s0p[isp][b][n][d] = sum_{i in chunk, p} W[i,n,d,p]*x[b,i,p]
// B-side now reads xt[i][b][p]: 16-lane 512-B contiguous segments.
// ---------------------------------------------------------------------------
__global__ __launch_bounds__(256) void k1_s0_mfma(const float* __restrict__ xt,
                                                  const float* __restrict__ W,
                                                  float* __restrict__ s0p)
{
    const int tid   = threadIdx.x;
    const int lane  = tid & 63;
    const int wv    = tid >> 6;
    const int col   = lane & 15;
    const int quad  = lane >> 4;
    const int b     = wv * 16 + col;
    const int nbase = blockIdx.x * 4;
    const int isp   = blockIdx.y;
    const int ibase = isp * CHUNK;

    f32x4 acc[4];
#pragma unroll
    for (int nn = 0; nn < 4; ++nn) acc[nn] = (f32x4){0.f, 0.f, 0.f, 0.f};

    const float* xlane = xt + (size_t)(ibase + quad) * (64 * P_) + b * P_;

    for (int ib = 0; ib < NIB; ++ib) {
        const int i0 = ibase + ib * 4;
        float4 xa = *(const float4*)(xlane);
        float4 xb = *(const float4*)(xlane + 4);
        xlane += 4 * 64 * P_;
        bf16x8 bhi, blo;
        split_frag(xa, xb, bhi, blo);
#pragma unroll
        for (int nn = 0; nn < 4; ++nn) {
            const float* wp = W + (((size_t)(i0 + quad) * N2_ + nbase + nn) * D_ + col) * P_;
            float4 wa = *(const float4*)wp;
            float4 wb = *(const float4*)(wp + 4);
            bf16x8 ahi, alo;
            split_frag(wa, wb, ahi, alo);
            acc[nn] = __builtin_amdgcn_mfma_f32_16x16x32_bf16(ahi, bhi, acc[nn], 0, 0, 0);
            acc[nn] = __builtin_amdgcn_mfma_f32_16x16x32_bf16(ahi, blo, acc[nn], 0, 0, 0);
            acc[nn] = __builtin_amdgcn_mfma_f32_16x16x32_bf16(alo, bhi, acc[nn], 0, 0, 0);
        }
    }
#pragma unroll
    for (int nn = 0; nn < 4; ++nn) {
        float4 v = make_float4(acc[nn][0], acc[nn][1], acc[nn][2], acc[nn][3]);
        *(float4*)(s0p + (size_t)isp * (B_ * N2_ * D_) + (size_t)b * (N2_ * D_)
                   + (nbase + nn) * D_ + quad * 4) = v;
    }
}

// ---------------------------------------------------------------------------
// K2/K4: reduce nsplit partials, scale, squash over d (16), write v.
// ---------------------------------------------------------------------------
__global__ __launch_bounds__(256) void k2_squash(const float* __restrict__ spart,
                                                 float* __restrict__ vout,
                                                 float scale, int nsplit)
{
    int idx = blockIdx.x * 256 + threadIdx.x;   // 0 .. 131071
    float s = 0.f;
    for (int sp = 0; sp < nsplit; ++sp)
        s += spart[(size_t)sp * (B_ * N2_ * D_) + idx];
    s *= scale;
    float sq = s * s;
    sq += __shfl_xor(sq, 1);
    sq += __shfl_xor(sq, 2);
    sq += __shfl_xor(sq, 4);
    sq += __shfl_xor(sq, 8);
    float norm = sqrtf(sq + 1.1920929e-7f);
    vout[idx] = (sq / (1.f + sq)) * (s / norm);
}

// ---------------------------------------------------------------------------
// K3A (MFMA 32x32x16): raw_t[i][n][b] = sum_d v0[b,n,d]*(sum_p W[i,n,d,p]*x[b,i,p])
// Same math as r8 (numerically validated). Epilogue x now: per i, two
// fully-coalesced 1-KB row loads of xt[i] + ds_bpermute redistribution
// (src lane = 2m+kh) instead of 64-line scatter loads.
// ---------------------------------------------------------------------------
__global__ __launch_bounds__(256, 4) void k3a_mfma32(const float* __restrict__ xt,
                                                     const float* __restrict__ W,
                                                     const float* __restrict__ v0,
                                                     float* __restrict__ raw_t)
{
    const int tid  = threadIdx.x;
    const int lane = tid & 63;
    const int wv   = tid >> 6;
    const int m    = lane & 31;
    const int kh   = lane >> 5;         // k-half (d-half) / p-half in epilogue
    const int isub = m >> 3;
    const int p    = m & 7;
    const int n    = blockIdx.x;
    const int ichunk = blockIdx.y * 64;
    const int src  = 2 * m + kh;        // bpermute source lane

    // B fragments (i-invariant): v0 for 2 b-tiles of 32, split once
    bf16x8 vhi[2], vlo[2];
#pragma unroll
    for (int bt = 0; bt < 2; ++bt) {
        const float* vp = v0 + (size_t)(bt * 32 + m) * (N2_ * D_) + n * D_ + kh * 8;
        float4 qa = *(const float4*)vp;
        float4 qb = *(const float4*)(vp + 4);
        split_frag(qa, qb, vhi[bt], vlo[bt]);
    }

#pragma unroll
    for (int k4 = 0; k4 < 4; ++k4) {
        const int i0 = ichunk + (wv + 4 * k4) * 4;      // 4 i's this iter
        // A gather: 8 dwords, stride 32 B, full-lane
        const float* wp = W + ((size_t)(i0 + isub) * N2_ + n) * (D_ * P_) + kh * 64 + p;
        float a[8];
#pragma unroll
        for (int j = 0; j < 8; ++j) a[j] = wp[8 * j];
        bf16x8 ahi, alo;
        split_arr(a, ahi, alo);

        f32x16 acc0, acc1;
#pragma unroll
        for (int r = 0; r < 16; ++r) { acc0[r] = 0.f; acc1[r] = 0.f; }
        acc0 = __builtin_amdgcn_mfma_f32_32x32x16_bf16(ahi, vhi[0], acc0, 0, 0, 0);
        acc0 = __builtin_amdgcn_mfma_f32_32x32x16_bf16(ahi, vlo[0], acc0, 0, 0, 0);
        acc0 = __builtin_amdgcn_mfma_f32_32x32x16_bf16(alo, vhi[0], acc0, 0, 0, 0);
        acc1 = __builtin_amdgcn_mfma_f32_32x32x16_bf16(ahi, vhi[1], acc1, 0, 0, 0);
        acc1 = __builtin_amdgcn_mfma_f32_32x32x16_bf16(ahi, vlo[1], acc1, 0, 0, 0);
        acc1 = __builtin_amdgcn_mfma_f32_32x32x16_bf16(alo, vhi[1], acc1, 0, 0, 0);

#pragma unroll
        for (int is = 0; is < 4; ++is) {
            // coalesced: xt row for i0+is is 2 KB; two 1-KB halves
            const float4* xrow = (const float4*)(xt + (size_t)(i0 + is) * (64 * P_));
            float4 xl0 = xrow[lane];        // f4 idx l: b=l>>1, ph=l&1 (b 0..31)
            float4 xl1 = xrow[64 + lane];   // b 32..63
            // lane (m,kh,bt) needs f4 (b=bt*32+m, ph=kh) -> src lane 2m+kh
            float4 xs0, xs1;
            xs0.x = __shfl(xl0.x, src); xs0.y = __shfl(xl0.y, src);
            xs0.z = __shfl(xl0.z, src); xs0.w = __shfl(xl0.w, src);
            xs1.x = __shfl(xl1.x, src); xs1.y = __shfl(xl1.y, src);
            xs1.z = __shfl(xl1.z, src); xs1.w = __shfl(xl1.w, src);

            float r0 = acc0[4 * is] * xs0.x + acc0[4 * is + 1] * xs0.y
                     + acc0[4 * is + 2] * xs0.z + acc0[4 * is + 3] * xs0.w;
            float r1 = acc1[4 * is] * xs1.x + acc1[4 * is + 1] * xs1.y
                     + acc1[4 * is + 2] * xs1.z + acc1[4 * is + 3] * xs1.w;
            r0 += __shfl_xor(r0, 32);
            r1 += __shfl_xor(r1, 32);
            if (kh == 0) {
                raw_t[(size_t)(i0 + is) * (N2_ * 64) + n * 64 + m]      = r0;
                raw_t[(size_t)(i0 + is) * (N2_ * 64) + n * 64 + 32 + m] = r1;
            }
        }
    }
}

// ---------------------------------------------------------------------------
// K3B_T: in-place softmax over n on raw_t[i][n][b] -> c_t[i][n][b].
// ---------------------------------------------------------------------------
__global__ __launch_bounds__(256) void k3b_t(float* __restrict__ rawc)
{
    const int i  = blockIdx.x;
    const int t  = threadIdx.x;
    const int b  = t & 63;
    const int ng = t >> 6;
    float* base = rawc + (size_t)i * (N2_ * 64) + b;

    float v[32];
    float m = -1e30f;
#pragma unroll
    for (int k = 0; k < 32; ++k) {
        v[k] = base[(ng * 32 + k) * 64];
        m = fmaxf(m, v[k]);
    }
    __shared__ float red[4][64];
    red[ng][b] = m;
    __syncthreads();
    m = fmaxf(fmaxf(red[0][b], red[1][b]), fmaxf(red[2][b], red[3][b]));
    float s = 0.f;
#pragma unroll
    for (int k = 0; k < 32; ++k) { v[k] = __expf(v[k] - m); s += v[k]; }
    __syncthreads();
    red[ng][b] = s;
    __syncthreads();
    s = red[0][b] + red[1][b] + red[2][b] + red[3][b];
    float inv = 1.f / s;
#pragma unroll
    for (int k = 0; k < 32; ++k)
        base[(ng * 32 + k) * 64] = v[k] * inv;
}

// ---------------------------------------------------------------------------
// K3C (MFMA): s1p[isp][b][n][d] = sum_{i,p} W[i,n,d,p]*c[b,i,n]*x[b,i,p]
// x via xt (coalesced 512-B segments).
// ---------------------------------------------------------------------------
__global__ __launch_bounds__(256) void k3c_s1_mfma(const float* __restrict__ xt,
                                                   const float* __restrict__ W,
                                                   const float* __restrict__ c_t,
                                                   float* __restrict__ s1p)
{
    const int tid   = threadIdx.x;
    const int lane  = tid & 63;
    const int wv    = tid >> 6;
    const int col   = lane & 15;
    const int quad  = lane >> 4;
    const int n     = blockIdx.x * 4 + wv;
    const int isp   = blockIdx.y;
    const int ibase = isp * CHUNK;

    f32x4 acc[4];
#pragma unroll
    for (int bt = 0; bt < 4; ++bt) acc[bt] = (f32x4){0.f, 0.f, 0.f, 0.f};

    for (int ib = 0; ib < NIB; ++ib) {
        const int iq = ibase + ib * 4 + quad;
        const float* wp = W + ((size_t)iq * N2_ + n) * (D_ * P_) + col * P_;
        float4 wa = *(const float4*)wp;
        float4 wb = *(const float4*)(wp + 4);
        bf16x8 ahi, alo;
        split_frag(wa, wb, ahi, alo);
#pragma unroll
        for (int bt = 0; bt < 4; ++bt) {
            const int b = bt * 16 + col;
            const float* xp = xt + (size_t)iq * (64 * P_) + b * P_;
            float4 xa = *(const float4*)xp;
            float4 xb = *(const float4*)(xp + 4);
            float c = c_t[((size_t)iq * N2_ + n) * 64 + b];
            float4 ya = make_float4(xa.x * c, xa.y * c, xa.z * c, xa.w * c);
            float4 yb = make_float4(xb.x * c, xb.y * c, xb.z * c, xb.w * c);
            bf16x8 bhi, blo;
            split_frag(ya, yb, bhi, blo);
            acc[bt] = __builtin_amdgcn_mfma_f32_16x16x32_bf16(ahi, bhi, acc[bt], 0, 0, 0);
            acc[bt] = __builtin_amdgcn_mfma_f32_16x16x32_bf16(ahi, blo, acc[bt], 0, 0, 0);
            acc[bt] = __builtin_amdgcn_mfma_f32_16x16x32_bf16(alo, bhi, acc[bt], 0, 0, 0);
        }
    }
#pragma unroll
    for (int bt = 0; bt < 4; ++bt) {
        const int b = bt * 16 + col;
        float4 v = make_float4(acc[bt][0], acc[bt][1], acc[bt][2], acc[bt][3]);
        *(float4*)(s1p + (size_t)isp * (B_ * N2_ * D_) + (size_t)b * (N2_ * D_)
                   + n * D_ + quad * 4) = v;
    }
}

// ---------------------------------------------------------------------------
extern "C" void kernel_launch(void* const* d_in, const int* in_sizes, int n_in,
                              void* d_out, int out_size, void* d_ws, size_t ws_size,
                              hipStream_t stream)
{
    const float* x = (const float*)d_in[0];   // [64,1152,8]
    const float* W = (const float*)d_in[1];   // [1152,128,16,8]
    float* out = (float*)d_out;               // [64,128,16]

    float* s_part = (float*)d_ws;                               // 32*131072 floats (16.8 MB)
    float* v0     = s_part + (size_t)NSPLIT * B_ * N2_ * D_;    // 131072 floats
    float* c_t    = v0 + B_ * N2_ * D_;                         // 9437184 floats: raw_t then (in-place) c_t, [i][n][b]
    float* xt     = c_t + (size_t)N1_ * N2_ * 64;               // 589824 floats: x transposed [i][b][p]

    k0_xt       <<<N1_,              128, 0, stream>>>(x, xt);
    k1_s0_mfma  <<<dim3(32, NSPLIT), 256, 0, stream>>>(xt, W, s_part);
    k2_squash   <<<512,              256, 0, stream>>>(s_part, v0, 1.f / 128.f, NSPLIT);
    k3a_mfma32  <<<dim3(128, 18),    256, 0, stream>>>(xt, W, v0, c_t);
    k3b_t       <<<N1_,              256, 0, stream>>>(c_t);
    k3c_s1_mfma <<<dim3(32, NSPLIT), 256, 0, stream>>>(xt, W, c_t, s_part);
    k2_squash   <<<512,              256, 0, stream>>>(s_part, out, 1.f, NSPLIT);
}